// Round 1
// baseline (51.739 us; speedup 1.0000x reference)
//
#include <hip/hip_runtime.h>
#include <hip/hip_bf16.h>

#define EPSF 1e-9f
#define INV_PI2_4 0.40528473456935109f   // 4 / pi^2

__device__ __forceinline__ float bf2f(unsigned short h) {
    return __uint_as_float(((unsigned)h) << 16);
}
__device__ __forceinline__ unsigned short f2bf(float f) {
    unsigned u = __float_as_uint(f);
    u += 0x7FFFu + ((u >> 16) & 1u);   // round-to-nearest-even
    return (unsigned short)(u >> 16);
}

__device__ __forceinline__ float ciou_one(float x1a, float y1a, float x2a, float y2a,
                                          float x1b, float y1b, float x2b, float y2b) {
    float xmin = fmaxf(x1a, x1b), ymin = fmaxf(y1a, y1b);
    float xmax = fminf(x2a, x2b), ymax = fminf(y2a, y2b);
    float inter = fmaxf(xmax - xmin, 0.0f) * fmaxf(ymax - ymin, 0.0f);
    float wa = x2a - x1a, ha = y2a - y1a;
    float wb = x2b - x1b, hb = y2b - y1b;
    float uni = wa * ha + wb * hb - inter;
    float iou = inter / (uni + EPSF);
    float dx = (x1a + x2a) - (x1b + x2b);
    float dy = (y1a + y2a) - (y1b + y2b);
    float cd = 0.25f * (dx * dx + dy * dy);
    float cw = fmaxf(x2a, x2b) - fminf(x1a, x1b);
    float ch = fmaxf(y2a, y2b) - fminf(y1a, y1b);
    float diag = cw * cw + ch * ch + EPSF;
    float diou = iou - cd / diag;
    float at = atanf(wa / (ha + EPSF)) - atanf(wb / (hb + EPSF));
    float v = INV_PI2_4 * at * at;
    float alpha = v / (v - iou + 1.0f + EPSF);
    return diou - alpha * v;
}

// ---------------- dtype detection (device-side, deterministic) ----------------
// flags[0]: 0 = float32 boxes, 1 = packed bf16 boxes
// flags[1]: 0 = int32 mask,    1 = byte (bool) mask
__global__ void detect_kernel(const float* pred_f32, const int* mask_i32, int* flags) {
    if (blockIdx.x != 0 || threadIdx.x != 0) return;
    // If fp32: words 4k..4k+3 are x1,y1,x2,y2 of one box -> width/height in [1,100].
    // If bf16-packed: fp32(word[j]) ~ value of bf16 element 2j+1 (y coords of
    // unrelated boxes) -> differences rarely land in (0.5, 101).
    int ok = 0;
    for (int k = 0; k < 64; ++k) {
        float w = pred_f32[4 * k + 2] - pred_f32[4 * k + 0];
        float h = pred_f32[4 * k + 3] - pred_f32[4 * k + 1];
        if (w > 0.5f && w < 101.0f && h > 0.5f && h < 101.0f) ok++;
    }
    flags[0] = (ok >= 56) ? 0 : 1;
    // int32 mask: first 64 words all in {0,1}. Packed bools: P(word<=1) = 1/8 each.
    int allbin = 1;
    for (int k = 0; k < 64; ++k) {
        unsigned v = (unsigned)mask_i32[k];
        if (v > 1u) { allbin = 0; break; }
    }
    flags[1] = allbin ? 0 : 1;
}

// ---------------- main elementwise kernel ----------------
template <int DT, int MT>
__device__ __forceinline__ void run_body(const void* pred, const void* targ, const void* maskp,
                                         void* out, int n, float& lsum, float& csum) {
    int tid = blockIdx.x * blockDim.x + threadIdx.x;
    int stride = gridDim.x * blockDim.x;
    for (int i = tid; i < n; i += stride) {
        float x1a, y1a, x2a, y2a, x1b, y1b, x2b, y2b;
        if constexpr (DT == 0) {
            float4 p = ((const float4*)pred)[i];
            float4 t = ((const float4*)targ)[i];
            x1a = p.x; y1a = p.y; x2a = p.z; y2a = p.w;
            x1b = t.x; y1b = t.y; x2b = t.z; y2b = t.w;
        } else {
            ushort4 p = ((const ushort4*)pred)[i];
            ushort4 t = ((const ushort4*)targ)[i];
            x1a = bf2f(p.x); y1a = bf2f(p.y); x2a = bf2f(p.z); y2a = bf2f(p.w);
            x1b = bf2f(t.x); y1b = bf2f(t.y); x2b = bf2f(t.z); y2b = bf2f(t.w);
        }
        float m;
        if constexpr (MT == 0) m = (((const int*)maskp)[i] != 0) ? 1.0f : 0.0f;
        else                   m = (((const unsigned char*)maskp)[i] != 0) ? 1.0f : 0.0f;

        float c  = ciou_one(x1a, y1a, x2a, y2a, x1b, y1b, x2b, y2b);
        float cm = c * m;
        if constexpr (DT == 0) ((float*)out)[1 + i] = cm;
        else                   ((unsigned short*)out)[1 + i] = f2bf(cm);
        lsum += (1.0f - c) * m;
        csum += m;
    }
}

__global__ __launch_bounds__(256) void ciou_kernel(const void* pred, const void* targ,
                                                   const void* maskp, void* out, int n,
                                                   float* part_loss, float* part_cnt,
                                                   const int* flags) {
    int dt = flags[0], mt = flags[1];
    float lsum = 0.0f, csum = 0.0f;
    if (dt == 0) {
        if (mt == 0) run_body<0, 0>(pred, targ, maskp, out, n, lsum, csum);
        else         run_body<0, 1>(pred, targ, maskp, out, n, lsum, csum);
    } else {
        if (mt == 0) run_body<1, 0>(pred, targ, maskp, out, n, lsum, csum);
        else         run_body<1, 1>(pred, targ, maskp, out, n, lsum, csum);
    }
    // wave (64-lane) reduction
    for (int off = 32; off > 0; off >>= 1) {
        lsum += __shfl_down(lsum, off);
        csum += __shfl_down(csum, off);
    }
    __shared__ float sl[4], sc[4];
    int w = threadIdx.x >> 6, lane = threadIdx.x & 63;
    if (lane == 0) { sl[w] = lsum; sc[w] = csum; }
    __syncthreads();
    if (threadIdx.x == 0) {
        part_loss[blockIdx.x] = sl[0] + sl[1] + sl[2] + sl[3];
        part_cnt[blockIdx.x]  = sc[0] + sc[1] + sc[2] + sc[3];
    }
}

// ---------------- finalize: deterministic fixed-order sum ----------------
__global__ __launch_bounds__(256) void finalize_kernel(const float* part_loss, const float* part_cnt,
                                                       void* out, int nb, const int* flags) {
    __shared__ double sl[256], sc[256];
    double l = 0.0, c = 0.0;
    for (int i = threadIdx.x; i < nb; i += 256) {
        l += (double)part_loss[i];
        c += (double)part_cnt[i];
    }
    sl[threadIdx.x] = l; sc[threadIdx.x] = c;
    __syncthreads();
    for (int s = 128; s > 0; s >>= 1) {
        if (threadIdx.x < s) { sl[threadIdx.x] += sl[threadIdx.x + s]; sc[threadIdx.x] += sc[threadIdx.x + s]; }
        __syncthreads();
    }
    if (threadIdx.x == 0) {
        float loss = (float)(sl[0] / fmax(sc[0], 1.0));
        if (flags[0] == 0) ((float*)out)[0] = loss;
        else               ((unsigned short*)out)[0] = f2bf(loss);
    }
}

extern "C" void kernel_launch(void* const* d_in, const int* in_sizes, int n_in,
                              void* d_out, int out_size, void* d_ws, size_t ws_size,
                              hipStream_t stream) {
    const void* pred  = d_in[0];
    const void* targ  = d_in[1];
    const void* maskp = d_in[2];
    int n = in_sizes[0] / 4;   // number of boxes

    int*   flags = (int*)d_ws;
    int nblocks = 2048;
    size_t need = 64 + (size_t)nblocks * 2 * sizeof(float);
    if (ws_size < need && ws_size > 128) {
        nblocks = (int)((ws_size - 64) / (2 * sizeof(float)));
        if (nblocks > 2048) nblocks = 2048;
        if (nblocks < 1) nblocks = 1;
    }
    float* part_loss = (float*)((char*)d_ws + 64);
    float* part_cnt  = part_loss + nblocks;

    detect_kernel<<<1, 64, 0, stream>>>((const float*)pred, (const int*)maskp, flags);
    ciou_kernel<<<nblocks, 256, 0, stream>>>(pred, targ, maskp, d_out, n,
                                             part_loss, part_cnt, flags);
    finalize_kernel<<<1, 256, 0, stream>>>(part_loss, part_cnt, d_out, nblocks, flags);
}

// Round 2
// 41.875 us; speedup vs baseline: 1.2356x; 1.2356x over previous
//
#include <hip/hip_runtime.h>
#include <hip/hip_bf16.h>

typedef unsigned short ushort8_t __attribute__((ext_vector_type(8)));

constexpr float EPSF      = 1e-9f;
constexpr float HALF_PI_F = 1.5707963267948966f;
constexpr float INV_PI2_4 = 0.40528473456935109f;   // 4 / pi^2

__device__ __forceinline__ float bf2f(unsigned short h) {
    return __uint_as_float(((unsigned)h) << 16);
}
__device__ __forceinline__ unsigned short f2bf(float f) {
    unsigned u = __float_as_uint(f);
    u += 0x7FFFu + ((u >> 16) & 1u);   // round-to-nearest-even
    return (unsigned short)(u >> 16);
}
__device__ __forceinline__ float fast_rcp(float x) { return __builtin_amdgcn_rcpf(x); }

// minimax atan on [0,1], extended by atan(x) = pi/2 - atan(1/x); max err ~1e-6
__device__ __forceinline__ float fast_atan(float t) {
    float a = fabsf(t);
    bool big = a > 1.0f;
    float x = big ? fast_rcp(a) : a;
    float s = x * x;
    float p = -0.0117212f;
    p = fmaf(p, s, 0.05265332f);
    p = fmaf(p, s, -0.11643287f);
    p = fmaf(p, s, 0.19354346f);
    p = fmaf(p, s, -0.33262347f);
    p = fmaf(p, s, 0.99997726f);
    p = x * p;
    float r = big ? (HALF_PI_F - p) : p;
    return copysignf(r, t);
}

__device__ __forceinline__ float ciou_one(float x1a, float y1a, float x2a, float y2a,
                                          float x1b, float y1b, float x2b, float y2b) {
    float xmin = fmaxf(x1a, x1b), ymin = fmaxf(y1a, y1b);
    float xmax = fminf(x2a, x2b), ymax = fminf(y2a, y2b);
    float inter = fmaxf(xmax - xmin, 0.0f) * fmaxf(ymax - ymin, 0.0f);
    float wa = x2a - x1a, ha = y2a - y1a;
    float wb = x2b - x1b, hb = y2b - y1b;
    float uni = wa * ha + wb * hb - inter;
    float iou = inter * fast_rcp(uni + EPSF);
    float dx = (x1a + x2a) - (x1b + x2b);
    float dy = (y1a + y2a) - (y1b + y2b);
    float cd = 0.25f * (dx * dx + dy * dy);
    float cw = fmaxf(x2a, x2b) - fminf(x1a, x1b);
    float ch = fmaxf(y2a, y2b) - fminf(y1a, y1b);
    float diag = cw * cw + ch * ch + EPSF;
    // atan(wa/ha') - atan(wb/hb') == atan((wa*hb' - wb*ha')/(ha'*hb' + wa*wb))
    // (both operands >= 0 -> u*v >= 0 > -1, identity exact, result in (-pi/2, pi/2))
    float ha_ = ha + EPSF, hb_ = hb + EPSF;
    float at = fast_atan((wa * hb_ - wb * ha_) * fast_rcp(ha_ * hb_ + wa * wb + EPSF));
    float v = INV_PI2_4 * at * at;
    float av = v * v * fast_rcp(v - iou + 1.0f + EPSF);   // alpha * v
    return iou - cd * fast_rcp(diag) - av;
}

// ---------------- dtype detection (device-side, deterministic) ----------------
// flags[0]: 0 = float32 boxes, 1 = packed bf16 boxes
// flags[1]: 0 = int32 mask,    1 = byte (bool) mask
__global__ void detect_kernel(const float* pred_f32, const int* mask_i32, int* flags) {
    int lane = threadIdx.x & 63;   // 64 threads
    float w = pred_f32[4 * lane + 2] - pred_f32[4 * lane + 0];
    float h = pred_f32[4 * lane + 3] - pred_f32[4 * lane + 1];
    bool okbox = (w > 0.5f && w < 101.0f && h > 0.5f && h < 101.0f);
    unsigned long long b0 = __ballot(okbox);
    unsigned v = (unsigned)mask_i32[lane];
    unsigned long long b1 = __ballot(v <= 1u);
    if (lane == 0) {
        flags[0] = (__popcll(b0) >= 56) ? 0 : 1;
        flags[1] = (__popcll(b1) == 64) ? 0 : 1;
    }
}

// ---------------- main elementwise kernel: 4 boxes per thread ----------------
template <int DT, int MT>
__device__ __forceinline__ void do4(const void* pred, const void* targ, const void* maskp,
                                    void* out, int n, int t, float& lsum, float& csum) {
    int i0 = t << 2;
    float bx[4][8];   // all indices compile-time constant after unroll
    float mv[4];
    if (i0 + 4 <= n) {
        if constexpr (DT == 0) {
            const float4* P = (const float4*)pred;
            const float4* T = (const float4*)targ;
            #pragma unroll
            for (int k = 0; k < 4; ++k) {
                float4 p = P[i0 + k], q = T[i0 + k];
                bx[k][0] = p.x; bx[k][1] = p.y; bx[k][2] = p.z; bx[k][3] = p.w;
                bx[k][4] = q.x; bx[k][5] = q.y; bx[k][6] = q.z; bx[k][7] = q.w;
            }
        } else {
            const ushort8_t* P = (const ushort8_t*)pred;
            const ushort8_t* T = (const ushort8_t*)targ;
            ushort8_t pa = P[2 * t], pb = P[2 * t + 1];
            ushort8_t qa = T[2 * t], qb = T[2 * t + 1];
            #pragma unroll
            for (int j = 0; j < 4; ++j) {
                bx[0][j] = bf2f(pa[j]);     bx[1][j] = bf2f(pa[4 + j]);
                bx[2][j] = bf2f(pb[j]);     bx[3][j] = bf2f(pb[4 + j]);
                bx[0][4 + j] = bf2f(qa[j]); bx[1][4 + j] = bf2f(qa[4 + j]);
                bx[2][4 + j] = bf2f(qb[j]); bx[3][4 + j] = bf2f(qb[4 + j]);
            }
        }
        if constexpr (MT == 0) {
            int4 mi = ((const int4*)maskp)[t];
            mv[0] = (mi.x != 0) ? 1.0f : 0.0f; mv[1] = (mi.y != 0) ? 1.0f : 0.0f;
            mv[2] = (mi.z != 0) ? 1.0f : 0.0f; mv[3] = (mi.w != 0) ? 1.0f : 0.0f;
        } else {
            unsigned mu = ((const unsigned*)maskp)[t];
            #pragma unroll
            for (int k = 0; k < 4; ++k) mv[k] = ((mu >> (8 * k)) & 0xFFu) ? 1.0f : 0.0f;
        }
        #pragma unroll
        for (int k = 0; k < 4; ++k) {
            float c = ciou_one(bx[k][0], bx[k][1], bx[k][2], bx[k][3],
                               bx[k][4], bx[k][5], bx[k][6], bx[k][7]);
            float cm = c * mv[k];
            if constexpr (DT == 0) ((float*)out)[1 + i0 + k] = cm;
            else                   ((unsigned short*)out)[1 + i0 + k] = f2bf(cm);
            lsum += (1.0f - c) * mv[k];
            csum += mv[k];
        }
    } else {
        for (int i = i0; i < n; ++i) {
            float b[8];
            if constexpr (DT == 0) {
                const float* P = (const float*)pred; const float* T = (const float*)targ;
                #pragma unroll
                for (int j = 0; j < 4; ++j) { b[j] = P[4 * i + j]; b[4 + j] = T[4 * i + j]; }
            } else {
                const unsigned short* P = (const unsigned short*)pred;
                const unsigned short* T = (const unsigned short*)targ;
                #pragma unroll
                for (int j = 0; j < 4; ++j) { b[j] = bf2f(P[4 * i + j]); b[4 + j] = bf2f(T[4 * i + j]); }
            }
            float m;
            if constexpr (MT == 0) m = (((const int*)maskp)[i] != 0) ? 1.0f : 0.0f;
            else                   m = (((const unsigned char*)maskp)[i] != 0) ? 1.0f : 0.0f;
            float c = ciou_one(b[0], b[1], b[2], b[3], b[4], b[5], b[6], b[7]);
            float cm = c * m;
            if constexpr (DT == 0) ((float*)out)[1 + i] = cm;
            else                   ((unsigned short*)out)[1 + i] = f2bf(cm);
            lsum += (1.0f - c) * m;
            csum += m;
        }
    }
}

__global__ __launch_bounds__(256) void ciou_kernel(const void* pred, const void* targ,
                                                   const void* maskp, void* out, int n,
                                                   float* part_loss, float* part_cnt,
                                                   const int* flags) {
    int dt = flags[0], mt = flags[1];
    int nt = (n + 3) >> 2;
    int tid = blockIdx.x * blockDim.x + threadIdx.x;
    int stride = gridDim.x * blockDim.x;
    float lsum = 0.0f, csum = 0.0f;
    if (dt == 0) {
        if (mt == 0) { for (int t = tid; t < nt; t += stride) do4<0, 0>(pred, targ, maskp, out, n, t, lsum, csum); }
        else         { for (int t = tid; t < nt; t += stride) do4<0, 1>(pred, targ, maskp, out, n, t, lsum, csum); }
    } else {
        if (mt == 0) { for (int t = tid; t < nt; t += stride) do4<1, 0>(pred, targ, maskp, out, n, t, lsum, csum); }
        else         { for (int t = tid; t < nt; t += stride) do4<1, 1>(pred, targ, maskp, out, n, t, lsum, csum); }
    }
    // wave (64-lane) reduction
    for (int off = 32; off > 0; off >>= 1) {
        lsum += __shfl_down(lsum, off);
        csum += __shfl_down(csum, off);
    }
    __shared__ float sl[4], sc[4];
    int w = threadIdx.x >> 6, lane = threadIdx.x & 63;
    if (lane == 0) { sl[w] = lsum; sc[w] = csum; }
    __syncthreads();
    if (threadIdx.x == 0) {
        part_loss[blockIdx.x] = sl[0] + sl[1] + sl[2] + sl[3];
        part_cnt[blockIdx.x]  = sc[0] + sc[1] + sc[2] + sc[3];
    }
}

// ---------------- finalize: deterministic fixed-order sum ----------------
__global__ __launch_bounds__(256) void finalize_kernel(const float* part_loss, const float* part_cnt,
                                                       void* out, int nb, const int* flags) {
    __shared__ double sl[256], sc[256];
    double l = 0.0, c = 0.0;
    for (int i = threadIdx.x; i < nb; i += 256) {
        l += (double)part_loss[i];
        c += (double)part_cnt[i];
    }
    sl[threadIdx.x] = l; sc[threadIdx.x] = c;
    __syncthreads();
    for (int s = 128; s > 0; s >>= 1) {
        if (threadIdx.x < s) { sl[threadIdx.x] += sl[threadIdx.x + s]; sc[threadIdx.x] += sc[threadIdx.x + s]; }
        __syncthreads();
    }
    if (threadIdx.x == 0) {
        float loss = (float)(sl[0] / fmax(sc[0], 1.0));
        if (flags[0] == 0) ((float*)out)[0] = loss;
        else               ((unsigned short*)out)[0] = f2bf(loss);
    }
}

extern "C" void kernel_launch(void* const* d_in, const int* in_sizes, int n_in,
                              void* d_out, int out_size, void* d_ws, size_t ws_size,
                              hipStream_t stream) {
    const void* pred  = d_in[0];
    const void* targ  = d_in[1];
    const void* maskp = d_in[2];
    int n = in_sizes[0] / 4;       // number of boxes
    int nt = (n + 3) >> 2;         // 4 boxes per thread

    int* flags = (int*)d_ws;
    int nblocks = (nt + 255) / 256;
    if (nblocks > 4096) nblocks = 4096;
    size_t need = 64 + (size_t)nblocks * 2 * sizeof(float);
    if (ws_size < need && ws_size > 128) {
        nblocks = (int)((ws_size - 64) / (2 * sizeof(float)));
        if (nblocks < 1) nblocks = 1;
    }
    float* part_loss = (float*)((char*)d_ws + 64);
    float* part_cnt  = part_loss + nblocks;

    detect_kernel<<<1, 64, 0, stream>>>((const float*)pred, (const int*)maskp, flags);
    ciou_kernel<<<nblocks, 256, 0, stream>>>(pred, targ, maskp, d_out, n,
                                             part_loss, part_cnt, flags);
    finalize_kernel<<<1, 256, 0, stream>>>(part_loss, part_cnt, d_out, nblocks, flags);
}